// Round 2
// baseline (3189.458 us; speedup 1.0000x reference)
//
#include <hip/hip_runtime.h>
#include <hip/hip_bf16.h>

// Problem constants (match reference)
constexpr int N_NODES = 100000;
constexpr int N_EDGES = 500000;
constexpr int HID     = 128;   // conv1/conv2 output dim
constexpr int OUT_D   = 64;    // conv3 output dim

// ---------- degree kernels ----------
__global__ void fill_ones(float* __restrict__ p, int n) {
    int i = blockIdx.x * blockDim.x + threadIdx.x;
    if (i < n) p[i] = 1.0f;
}

__global__ void deg_count(const int* __restrict__ dst, float* __restrict__ deg, int e) {
    int i = blockIdx.x * blockDim.x + threadIdx.x;
    if (i < e) atomicAdd(&deg[dst[i]], 1.0f);
}

__global__ void deg_rsqrt(float* __restrict__ p, int n) {
    int i = blockIdx.x * blockDim.x + threadIdx.x;
    if (i < n) p[i] = rsqrtf(p[i]);   // p becomes deg^{-1/2}
}

// ---------- GEMM: Y[n,COLS] = X[n,128] @ W[128,COLS] (fp32) ----------
template <int COLS>
__global__ void gemm_kernel(const float* __restrict__ X,
                            const float* __restrict__ W,
                            float* __restrict__ Y, int n) {
    constexpr int ROWS = 16;
    __shared__ float xs[ROWS][128];
    const int r0 = blockIdx.x * ROWS;

    for (int idx = threadIdx.x; idx < ROWS * 128; idx += COLS) {
        const int r = idx >> 7, k = idx & 127;
        const int row = r0 + r;
        xs[r][k] = (row < n) ? X[(size_t)row * 128 + k] : 0.0f;
    }
    __syncthreads();

    const int c = threadIdx.x;
    float acc[ROWS];
#pragma unroll
    for (int r = 0; r < ROWS; ++r) acc[r] = 0.0f;

    for (int k = 0; k < 128; k += 4) {
        const float w0 = W[(size_t)(k + 0) * COLS + c];
        const float w1 = W[(size_t)(k + 1) * COLS + c];
        const float w2 = W[(size_t)(k + 2) * COLS + c];
        const float w3 = W[(size_t)(k + 3) * COLS + c];
#pragma unroll
        for (int r = 0; r < ROWS; ++r) {
            const float4 xv = *(const float4*)&xs[r][k];
            acc[r] = fmaf(xv.x, w0, fmaf(xv.y, w1, fmaf(xv.z, w2, fmaf(xv.w, w3, acc[r]))));
        }
    }

    for (int r = 0; r < ROWS; ++r) {
        const int row = r0 + r;
        if (row < n) Y[(size_t)row * COLS + c] = acc[r];
    }
}

// ---------- edge scatter: agg[dst] += lin[src] * dis[src]*dis[dst] ----------
template <int DIMS>
__global__ void scatter_add(const float* __restrict__ lin, float* __restrict__ agg,
                            const int* __restrict__ src, const int* __restrict__ dst,
                            const float* __restrict__ dis, int e) {
    constexpr int TPE = DIMS / 4;  // threads per edge, each does a float4
    const int tid = blockIdx.x * blockDim.x + threadIdx.x;
    const int edge = tid / TPE;
    const int ch   = tid % TPE;
    if (edge >= e) return;
    const int s = src[edge], d = dst[edge];
    const float norm = dis[s] * dis[d];
    const float4 v = *(const float4*)&lin[(size_t)s * DIMS + ch * 4];
    float* out = &agg[(size_t)d * DIMS + ch * 4];
    atomicAdd(out + 0, v.x * norm);
    atomicAdd(out + 1, v.y * norm);
    atomicAdd(out + 2, v.z * norm);
    atomicAdd(out + 3, v.w * norm);
}

// ---------- finalize conv1: hs = relu(agg + lin/deg + b), in-place into agg ----------
__global__ void finalize_relu(float* __restrict__ agg, const float* __restrict__ lin,
                              const float* __restrict__ dis,
                              const float* __restrict__ b, int n) {
    const size_t i = (size_t)blockIdx.x * blockDim.x + threadIdx.x;
    if (i >= (size_t)n * HID) return;
    const int node = (int)(i >> 7);
    const int col  = (int)(i & 127);
    const float ds = dis[node];
    const float inv = ds * ds;  // 1/deg
    float v = agg[i] + lin[i] * inv + b[col];
    agg[i] = v > 0.0f ? v : 0.0f;
}

// ---------- finalize conv3: z = agg + lin/deg + b ; write fp32 z to output ----------
__global__ void finalize_out(const float* __restrict__ agg, const float* __restrict__ lin,
                             const float* __restrict__ dis,
                             const float* __restrict__ b,
                             float* __restrict__ Zout, int n) {
    const size_t i = (size_t)blockIdx.x * blockDim.x + threadIdx.x;
    if (i >= (size_t)n * OUT_D) return;
    const int node = (int)(i >> 6);
    const int col  = (int)(i & 63);
    const float ds = dis[node];
    const float inv = ds * ds;
    Zout[i] = agg[i] + lin[i] * inv + b[col];
}

// ---------- decoder: p[e] = sigmoid(dot(Z[src], Z[dst])) over 64 dims ----------
__global__ void decoder_kernel(const float* __restrict__ Z,
                               const int* __restrict__ src, const int* __restrict__ dst,
                               float* __restrict__ outp, int e) {
    const int tid = blockIdx.x * blockDim.x + threadIdx.x;
    const int edge = tid >> 4;   // 16 lanes per edge
    const int lane = tid & 15;
    if (edge >= e) return;
    const int s = src[edge], d = dst[edge];
    const float4 a = *(const float4*)&Z[(size_t)s * OUT_D + lane * 4];
    const float4 b = *(const float4*)&Z[(size_t)d * OUT_D + lane * 4];
    float p = a.x * b.x + a.y * b.y + a.z * b.z + a.w * b.w;
    p += __shfl_down(p, 8, 16);
    p += __shfl_down(p, 4, 16);
    p += __shfl_down(p, 2, 16);
    p += __shfl_down(p, 1, 16);
    if (lane == 0) outp[edge] = 1.0f / (1.0f + expf(-p));
}

extern "C" void kernel_launch(void* const* d_in, const int* in_sizes, int n_in,
                              void* d_out, int out_size, void* d_ws, size_t ws_size,
                              hipStream_t stream) {
    const float* xs  = (const float*)d_in[0];
    const float* xt  = (const float*)d_in[1];
    const int* s_ei  = (const int*)d_in[2];
    const int* t_ei  = (const int*)d_in[3];
    const float* W1  = (const float*)d_in[4];
    const float* b1  = (const float*)d_in[5];
    const float* W2  = (const float*)d_in[6];
    const float* b2  = (const float*)d_in[7];
    const float* W3  = (const float*)d_in[8];
    const float* b3  = (const float*)d_in[9];

    float* ws = (float*)d_ws;
    float* A     = ws;                                  // N*128 (lin outputs)
    float* B     = A + (size_t)N_NODES * HID;           // N*128 (agg / hs)
    float* dis_s = B + (size_t)N_NODES * HID;           // N
    float* dis_t = dis_s + N_NODES;                     // N

    float* out = (float*)d_out;
    float* out_zs = out;                                 // N*64
    float* out_zt = out + (size_t)N_NODES * OUT_D;       // N*64
    float* out_ps = out + 2 * (size_t)N_NODES * OUT_D;   // E
    float* out_pt = out_ps + N_EDGES;                    // E

    auto run_net = [&](const float* x, const int* ei,
                       const float* Wl, const float* bl,
                       float* dis, float* oz, float* op) {
        const int* src = ei;
        const int* dst = ei + N_EDGES;

        fill_ones<<<(N_NODES + 255) / 256, 256, 0, stream>>>(dis, N_NODES);
        deg_count<<<(N_EDGES + 255) / 256, 256, 0, stream>>>(dst, dis, N_EDGES);
        deg_rsqrt<<<(N_NODES + 255) / 256, 256, 0, stream>>>(dis, N_NODES);

        // conv1/conv2: lin = x @ W  (N x 128)
        gemm_kernel<HID><<<(N_NODES + 15) / 16, HID, 0, stream>>>(x, Wl, A, N_NODES);
        hipMemsetAsync(B, 0, (size_t)N_NODES * HID * sizeof(float), stream);
        scatter_add<HID>
            <<<(int)(((size_t)N_EDGES * (HID / 4) + 255) / 256), 256, 0, stream>>>(
                A, B, src, dst, dis, N_EDGES);
        finalize_relu<<<(int)(((size_t)N_NODES * HID + 255) / 256), 256, 0, stream>>>(
            B, A, dis, bl, N_NODES);   // B := hs

        // conv3: lin = hs @ W3  (N x 64)
        gemm_kernel<OUT_D><<<(N_NODES + 15) / 16, OUT_D, 0, stream>>>(B, W3, A, N_NODES);
        hipMemsetAsync(B, 0, (size_t)N_NODES * OUT_D * sizeof(float), stream);
        scatter_add<OUT_D>
            <<<(int)(((size_t)N_EDGES * (OUT_D / 4) + 255) / 256), 256, 0, stream>>>(
                A, B, src, dst, dis, N_EDGES);
        finalize_out<<<(int)(((size_t)N_NODES * OUT_D + 255) / 256), 256, 0, stream>>>(
            B, A, dis, b3, oz, N_NODES);

        decoder_kernel<<<(int)(((size_t)N_EDGES * 16 + 255) / 256), 256, 0, stream>>>(
            oz, src, dst, op, N_EDGES);
    };

    run_net(xs, s_ei, W1, b1, dis_s, out_zs, out_ps);
    run_net(xt, t_ei, W2, b2, dis_t, out_zt, out_pt);
}

// Round 3
// 868.600 us; speedup vs baseline: 3.6720x; 3.6720x over previous
//
#include <hip/hip_runtime.h>
#include <hip/hip_bf16.h>

// Problem constants (match reference)
constexpr int N_NODES = 100000;
constexpr int N_EDGES = 500000;
constexpr int HID     = 128;   // conv1/conv2 output dim
constexpr int OUT_D   = 64;    // conv3 output dim

constexpr int SCAN_BLK   = 256;
constexpr int SCAN_ELEMS = 1024;                                   // 4 per thread
constexpr int NBLK_SCAN  = (N_NODES + SCAN_ELEMS - 1) / SCAN_ELEMS; // 98 (<=256)

// ---------- degree count (int atomics) ----------
__global__ void deg_count_i(const int* __restrict__ dst, int* __restrict__ deg, int e) {
    int i = blockIdx.x * blockDim.x + threadIdx.x;
    if (i < e) atomicAdd(&deg[dst[i]], 1);
}

// ---------- scan phase A: per-block sums of 1024 degrees ----------
__global__ void scan_block_sums(const int* __restrict__ deg, int* __restrict__ partial, int n) {
    __shared__ int sd[SCAN_BLK];
    const int base = blockIdx.x * SCAN_ELEMS;
    int sum = 0;
#pragma unroll
    for (int k = 0; k < 4; ++k) {
        const int idx = base + k * SCAN_BLK + threadIdx.x;
        if (idx < n) sum += deg[idx];
    }
    sd[threadIdx.x] = sum;
    __syncthreads();
    for (int o = SCAN_BLK / 2; o > 0; o >>= 1) {
        if (threadIdx.x < o) sd[threadIdx.x] += sd[threadIdx.x + o];
        __syncthreads();
    }
    if (threadIdx.x == 0) partial[blockIdx.x] = sd[0];
}

// ---------- scan phase B: exclusive-scan the (<=256) partials in place ----------
__global__ void scan_partials(int* __restrict__ partial, int np) {
    __shared__ int s[SCAN_BLK];
    const int t = threadIdx.x;
    const int v = (t < np) ? partial[t] : 0;
    s[t] = v;
    __syncthreads();
    for (int o = 1; o < SCAN_BLK; o <<= 1) {
        const int x = (t >= o) ? s[t - o] : 0;
        __syncthreads();
        if (t >= o) s[t] += x;
        __syncthreads();
    }
    if (t < np) partial[t] = s[t] - v;   // exclusive
}

// ---------- scan phase C: final offsets + cursor copy + dis = rsqrt(deg+1) ----------
__global__ void scan_final(const int* __restrict__ deg, const int* __restrict__ partial,
                           int* __restrict__ off, int* __restrict__ cur,
                           float* __restrict__ dis, int n) {
    __shared__ int s[SCAN_BLK];
    const int t = threadIdx.x;
    const int base = blockIdx.x * SCAN_ELEMS + t * 4;
    int d0 = 0, d1 = 0, d2 = 0, d3 = 0;
    if (base + 0 < n) d0 = deg[base + 0];
    if (base + 1 < n) d1 = deg[base + 1];
    if (base + 2 < n) d2 = deg[base + 2];
    if (base + 3 < n) d3 = deg[base + 3];
    const int ts = d0 + d1 + d2 + d3;
    s[t] = ts;
    __syncthreads();
    for (int o = 1; o < SCAN_BLK; o <<= 1) {
        const int x = (t >= o) ? s[t - o] : 0;
        __syncthreads();
        if (t >= o) s[t] += x;
        __syncthreads();
    }
    int ex = s[t] - ts + partial[blockIdx.x];
    const int o0 = ex, o1 = ex + d0, o2 = o1 + d1, o3 = o2 + d2;
    if (base + 0 < n) { off[base + 0] = o0; cur[base + 0] = o0; dis[base + 0] = rsqrtf((float)d0 + 1.0f); }
    if (base + 1 < n) { off[base + 1] = o1; cur[base + 1] = o1; dis[base + 1] = rsqrtf((float)d1 + 1.0f); }
    if (base + 2 < n) { off[base + 2] = o2; cur[base + 2] = o2; dis[base + 2] = rsqrtf((float)d2 + 1.0f); }
    if (base + 3 < n) { off[base + 3] = o3; cur[base + 3] = o3; dis[base + 3] = rsqrtf((float)d3 + 1.0f); }
}

// ---------- bucket edges by dst (CSR build) ----------
__global__ void bucket_edges(const int* __restrict__ src, const int* __restrict__ dst,
                             int* __restrict__ cur, int* __restrict__ ebuf, int e) {
    const int i = blockIdx.x * blockDim.x + threadIdx.x;
    if (i >= e) return;
    const int d = dst[i];
    const int pos = atomicAdd(&cur[d], 1);
    ebuf[pos] = src[i];
}

// ---------- GEMM: Y[n,COLS] = X[n,128] @ W[128,COLS] (fp32) ----------
template <int COLS>
__global__ void gemm_kernel(const float* __restrict__ X,
                            const float* __restrict__ W,
                            float* __restrict__ Y, int n) {
    constexpr int ROWS = 16;
    __shared__ float xs[ROWS][128];
    const int r0 = blockIdx.x * ROWS;

    for (int idx = threadIdx.x; idx < ROWS * 128; idx += COLS) {
        const int r = idx >> 7, k = idx & 127;
        const int row = r0 + r;
        xs[r][k] = (row < n) ? X[(size_t)row * 128 + k] : 0.0f;
    }
    __syncthreads();

    const int c = threadIdx.x;
    float acc[ROWS];
#pragma unroll
    for (int r = 0; r < ROWS; ++r) acc[r] = 0.0f;

    for (int k = 0; k < 128; k += 4) {
        const float w0 = W[(size_t)(k + 0) * COLS + c];
        const float w1 = W[(size_t)(k + 1) * COLS + c];
        const float w2 = W[(size_t)(k + 2) * COLS + c];
        const float w3 = W[(size_t)(k + 3) * COLS + c];
#pragma unroll
        for (int r = 0; r < ROWS; ++r) {
            const float4 xv = *(const float4*)&xs[r][k];
            acc[r] = fmaf(xv.x, w0, fmaf(xv.y, w1, fmaf(xv.z, w2, fmaf(xv.w, w3, acc[r]))));
        }
    }

    for (int r = 0; r < ROWS; ++r) {
        const int row = r0 + r;
        if (row < n) Y[(size_t)row * COLS + c] = acc[r];
    }
}

// ---------- gather conv (128-d): hs = relu(sum_nbr lin[s]*norm + lin[d]/deg + b) ----------
__global__ void gather_relu_128(const float* __restrict__ lin,
                                const int* __restrict__ off, const int* __restrict__ degc,
                                const int* __restrict__ ebuf, const float* __restrict__ dis,
                                const float* __restrict__ bias,
                                float* __restrict__ outp, int n) {
    const int node = blockIdx.x * 4 + (threadIdx.x >> 6);
    const int lane = threadIdx.x & 63;
    if (node >= n) return;
    const float ds = dis[node];
    const float inv = ds * ds;                 // 1/(deg+1)
    const float2* __restrict__ lin2 = (const float2*)lin;
    float2 acc = lin2[(size_t)node * 64 + lane];
    acc.x *= inv; acc.y *= inv;
    const int start = off[node];
    const int cnt = degc[node];
    for (int j = 0; j < cnt; ++j) {
        const int s = ebuf[start + j];
        const float nm = dis[s] * ds;
        const float2 v = lin2[(size_t)s * 64 + lane];
        acc.x = fmaf(v.x, nm, acc.x);
        acc.y = fmaf(v.y, nm, acc.y);
    }
    const float2 bb = ((const float2*)bias)[lane];
    acc.x += bb.x; acc.y += bb.y;
    acc.x = acc.x > 0.0f ? acc.x : 0.0f;
    acc.y = acc.y > 0.0f ? acc.y : 0.0f;
    ((float2*)outp)[(size_t)node * 64 + lane] = acc;
}

// ---------- gather conv (64-d): z = sum_nbr lin[s]*norm + lin[d]/deg + b ----------
__global__ void gather_out_64(const float* __restrict__ lin,
                              const int* __restrict__ off, const int* __restrict__ degc,
                              const int* __restrict__ ebuf, const float* __restrict__ dis,
                              const float* __restrict__ bias,
                              float* __restrict__ outp, int n) {
    const int node = blockIdx.x * 4 + (threadIdx.x >> 6);
    const int lane = threadIdx.x & 63;
    if (node >= n) return;
    const float ds = dis[node];
    const float inv = ds * ds;
    float acc = lin[(size_t)node * 64 + lane] * inv;
    const int start = off[node];
    const int cnt = degc[node];
    for (int j = 0; j < cnt; ++j) {
        const int s = ebuf[start + j];
        const float nm = dis[s] * ds;
        acc = fmaf(lin[(size_t)s * 64 + lane], nm, acc);
    }
    outp[(size_t)node * 64 + lane] = acc + bias[lane];
}

// ---------- decoder: p[e] = sigmoid(dot(Z[src], Z[dst])) over 64 dims ----------
__global__ void decoder_kernel(const float* __restrict__ Z,
                               const int* __restrict__ src, const int* __restrict__ dst,
                               float* __restrict__ outp, int e) {
    const int tid = blockIdx.x * blockDim.x + threadIdx.x;
    const int edge = tid >> 4;   // 16 lanes per edge
    const int lane = tid & 15;
    if (edge >= e) return;
    const int s = src[edge], d = dst[edge];
    const float4 a = *(const float4*)&Z[(size_t)s * OUT_D + lane * 4];
    const float4 b = *(const float4*)&Z[(size_t)d * OUT_D + lane * 4];
    float p = a.x * b.x + a.y * b.y + a.z * b.z + a.w * b.w;
    p += __shfl_down(p, 8, 16);
    p += __shfl_down(p, 4, 16);
    p += __shfl_down(p, 2, 16);
    p += __shfl_down(p, 1, 16);
    if (lane == 0) outp[edge] = 1.0f / (1.0f + expf(-p));
}

extern "C" void kernel_launch(void* const* d_in, const int* in_sizes, int n_in,
                              void* d_out, int out_size, void* d_ws, size_t ws_size,
                              hipStream_t stream) {
    const float* xs  = (const float*)d_in[0];
    const float* xt  = (const float*)d_in[1];
    const int* s_ei  = (const int*)d_in[2];
    const int* t_ei  = (const int*)d_in[3];
    const float* W1  = (const float*)d_in[4];
    const float* b1  = (const float*)d_in[5];
    const float* W2  = (const float*)d_in[6];
    const float* b2  = (const float*)d_in[7];
    const float* W3  = (const float*)d_in[8];
    const float* b3  = (const float*)d_in[9];

    // workspace layout (~107 MB)
    float* ws = (float*)d_ws;
    float* A       = ws;                                  // N*128 f
    float* B       = A + (size_t)N_NODES * HID;           // N*128 f
    float* dis     = B + (size_t)N_NODES * HID;           // N f
    int*   deg_i   = (int*)(dis + N_NODES);               // N i
    int*   off     = deg_i + N_NODES;                     // N i
    int*   cur     = off + N_NODES;                       // N i
    int*   partial = cur + N_NODES;                       // 256 i
    int*   ebuf    = partial + 256;                       // E i

    float* out = (float*)d_out;
    float* out_zs = out;                                 // N*64
    float* out_zt = out + (size_t)N_NODES * OUT_D;       // N*64
    float* out_ps = out + 2 * (size_t)N_NODES * OUT_D;   // E
    float* out_pt = out_ps + N_EDGES;                    // E

    const int nodeBlocks = (N_NODES + 3) / 4;            // 4 nodes (waves) per block

    auto run_net = [&](const float* x, const int* ei,
                       const float* Wl, const float* bl,
                       float* oz, float* op) {
        const int* src = ei;
        const int* dst = ei + N_EDGES;

        // ---- CSR build (shared by both convs of this network) ----
        hipMemsetAsync(deg_i, 0, (size_t)N_NODES * sizeof(int), stream);
        deg_count_i<<<(N_EDGES + 255) / 256, 256, 0, stream>>>(dst, deg_i, N_EDGES);
        scan_block_sums<<<NBLK_SCAN, SCAN_BLK, 0, stream>>>(deg_i, partial, N_NODES);
        scan_partials<<<1, SCAN_BLK, 0, stream>>>(partial, NBLK_SCAN);
        scan_final<<<NBLK_SCAN, SCAN_BLK, 0, stream>>>(deg_i, partial, off, cur, dis, N_NODES);
        bucket_edges<<<(N_EDGES + 255) / 256, 256, 0, stream>>>(src, dst, cur, ebuf, N_EDGES);

        // ---- conv1/conv2: lin = x @ W (N x 128); gather+relu -> B ----
        gemm_kernel<HID><<<(N_NODES + 15) / 16, HID, 0, stream>>>(x, Wl, A, N_NODES);
        gather_relu_128<<<nodeBlocks, 256, 0, stream>>>(A, off, deg_i, ebuf, dis, bl, B, N_NODES);

        // ---- conv3: lin = hs @ W3 (N x 64); gather -> z (directly to output) ----
        gemm_kernel<OUT_D><<<(N_NODES + 15) / 16, OUT_D, 0, stream>>>(B, W3, A, N_NODES);
        gather_out_64<<<nodeBlocks, 256, 0, stream>>>(A, off, deg_i, ebuf, dis, b3, oz, N_NODES);

        // ---- decoder ----
        decoder_kernel<<<(int)(((size_t)N_EDGES * 16 + 255) / 256), 256, 0, stream>>>(
            oz, src, dst, op, N_EDGES);
    };

    run_net(xs, s_ei, W1, b1, out_zs, out_ps);
    run_net(xt, t_ei, W2, b2, out_zt, out_pt);
}

// Round 4
// 680.834 us; speedup vs baseline: 4.6846x; 1.2758x over previous
//
#include <hip/hip_runtime.h>
#include <hip/hip_bf16.h>

// Problem constants (match reference)
constexpr int N_NODES = 100000;
constexpr int N_EDGES = 500000;
constexpr int HID     = 128;   // conv1/conv2 output dim
constexpr int OUT_D   = 64;    // conv3 output dim

constexpr int ROW_BLKS = (N_NODES + 63) / 64;   // 1563 blocks of 64 rows
constexpr int N_PAD    = ROW_BLKS * 64;          // 100032 padded rows

constexpr int SCAN_BLK   = 256;
constexpr int SCAN_ELEMS = 1024;                                    // 4 per thread
constexpr int NBLK_SCAN  = (N_NODES + SCAN_ELEMS - 1) / SCAN_ELEMS; // 98 (<=256)

typedef __attribute__((ext_vector_type(8))) short short8;
typedef __attribute__((ext_vector_type(4))) float float4v;

// float -> bf16 (round-to-nearest-even), as raw ushort
__device__ __forceinline__ unsigned short f2bf(float f) {
    unsigned u = __float_as_uint(f);
    u += 0x7fffu + ((u >> 16) & 1u);
    return (unsigned short)(u >> 16);
}

// ---------- degree count (int atomics) ----------
__global__ void deg_count_i(const int* __restrict__ dst, int* __restrict__ deg, int e) {
    int i = blockIdx.x * blockDim.x + threadIdx.x;
    if (i < e) atomicAdd(&deg[dst[i]], 1);
}

// ---------- scan phase A: per-block sums of 1024 degrees ----------
__global__ void scan_block_sums(const int* __restrict__ deg, int* __restrict__ partial, int n) {
    __shared__ int sd[SCAN_BLK];
    const int base = blockIdx.x * SCAN_ELEMS;
    int sum = 0;
#pragma unroll
    for (int k = 0; k < 4; ++k) {
        const int idx = base + k * SCAN_BLK + threadIdx.x;
        if (idx < n) sum += deg[idx];
    }
    sd[threadIdx.x] = sum;
    __syncthreads();
    for (int o = SCAN_BLK / 2; o > 0; o >>= 1) {
        if (threadIdx.x < o) sd[threadIdx.x] += sd[threadIdx.x + o];
        __syncthreads();
    }
    if (threadIdx.x == 0) partial[blockIdx.x] = sd[0];
}

// ---------- scan phase B: exclusive-scan the (<=256) partials in place ----------
__global__ void scan_partials(int* __restrict__ partial, int np) {
    __shared__ int s[SCAN_BLK];
    const int t = threadIdx.x;
    const int v = (t < np) ? partial[t] : 0;
    s[t] = v;
    __syncthreads();
    for (int o = 1; o < SCAN_BLK; o <<= 1) {
        const int x = (t >= o) ? s[t - o] : 0;
        __syncthreads();
        if (t >= o) s[t] += x;
        __syncthreads();
    }
    if (t < np) partial[t] = s[t] - v;   // exclusive
}

// ---------- scan phase C: final offsets + cursor copy + dis = rsqrt(deg+1) ----------
__global__ void scan_final(const int* __restrict__ deg, const int* __restrict__ partial,
                           int* __restrict__ off, int* __restrict__ cur,
                           float* __restrict__ dis, int n) {
    __shared__ int s[SCAN_BLK];
    const int t = threadIdx.x;
    const int base = blockIdx.x * SCAN_ELEMS + t * 4;
    int d0 = 0, d1 = 0, d2 = 0, d3 = 0;
    if (base + 0 < n) d0 = deg[base + 0];
    if (base + 1 < n) d1 = deg[base + 1];
    if (base + 2 < n) d2 = deg[base + 2];
    if (base + 3 < n) d3 = deg[base + 3];
    const int ts = d0 + d1 + d2 + d3;
    s[t] = ts;
    __syncthreads();
    for (int o = 1; o < SCAN_BLK; o <<= 1) {
        const int x = (t >= o) ? s[t - o] : 0;
        __syncthreads();
        if (t >= o) s[t] += x;
        __syncthreads();
    }
    int ex = s[t] - ts + partial[blockIdx.x];
    const int o0 = ex, o1 = ex + d0, o2 = o1 + d1, o3 = o2 + d2;
    if (base + 0 < n) { off[base + 0] = o0; cur[base + 0] = o0; dis[base + 0] = rsqrtf((float)d0 + 1.0f); }
    if (base + 1 < n) { off[base + 1] = o1; cur[base + 1] = o1; dis[base + 1] = rsqrtf((float)d1 + 1.0f); }
    if (base + 2 < n) { off[base + 2] = o2; cur[base + 2] = o2; dis[base + 2] = rsqrtf((float)d2 + 1.0f); }
    if (base + 3 < n) { off[base + 3] = o3; cur[base + 3] = o3; dis[base + 3] = rsqrtf((float)d3 + 1.0f); }
}

// ---------- bucket edges by dst (CSR build) ----------
__global__ void bucket_edges(const int* __restrict__ src, const int* __restrict__ dst,
                             int* __restrict__ cur, int* __restrict__ ebuf, int e) {
    const int i = blockIdx.x * blockDim.x + threadIdx.x;
    if (i >= e) return;
    const int d = dst[i];
    const int pos = atomicAdd(&cur[d], 1);
    ebuf[pos] = src[i];
}

// ---------- fp32 -> bf16 conversion (x features) ----------
__global__ void convert_bf16(const float* __restrict__ X, unsigned short* __restrict__ Xb,
                             int n4) {
    const int i = blockIdx.x * blockDim.x + threadIdx.x;
    if (i >= n4) return;
    const float4 v = ((const float4*)X)[i];
    ushort4 o;
    o.x = f2bf(v.x); o.y = f2bf(v.y); o.z = f2bf(v.z); o.w = f2bf(v.w);
    ((ushort4*)Xb)[i] = o;
}

// ---------- pack W[128,COLS] fp32 into MFMA B-fragment order, bf16 ----------
// b_frag for lane(n), kb: Wp[((kb*4+quad)*COLS + n)*8 + j] = W[kb*32+quad*8+j][n]
template <int COLS>
__global__ void pack_w(const float* __restrict__ W, unsigned short* __restrict__ Wp) {
    const int idx = blockIdx.x * blockDim.x + threadIdx.x;  // k*COLS + n
    if (idx >= 128 * COLS) return;
    const int k = idx / COLS, nn = idx % COLS;
    const int kb = k >> 5, rem = k & 31, quad = rem >> 3, j = rem & 7;
    Wp[((size_t)(kb * 4 + quad) * COLS + nn) * 8 + j] = f2bf(W[idx]);
}

// ---------- MFMA GEMM: Y[n,COLS] = Xb[n,128](bf16) @ Wp(bf16, packed), fp32 out ----
// One wave per 16-row stripe; wave loops all COLS/16 col-tiles; A frags loaded once.
template <int COLS>
__global__ __launch_bounds__(256) void mfma_gemm(const unsigned short* __restrict__ Xb,
                                                 const unsigned short* __restrict__ Wp,
                                                 float* __restrict__ Y, int n) {
    const int wave = threadIdx.x >> 6;
    const int lane = threadIdx.x & 63;
    const int quad = lane >> 4;
    const int l16  = lane & 15;
    const int rowbase = blockIdx.x * 64 + wave * 16;

    // A fragments: A[m=l16][k=kb*32+quad*8+j], 16B contiguous each
    short8 a[4];
    const size_t arow = (size_t)(rowbase + l16) * 128;
#pragma unroll
    for (int kb = 0; kb < 4; ++kb)
        a[kb] = *(const short8*)&Xb[arow + kb * 32 + quad * 8];

#pragma unroll
    for (int ct = 0; ct < COLS / 16; ++ct) {
        const int col = ct * 16 + l16;
        float4v acc = {0.0f, 0.0f, 0.0f, 0.0f};
#pragma unroll
        for (int kb = 0; kb < 4; ++kb) {
            const short8 b = *(const short8*)&Wp[((size_t)(kb * 4 + quad) * COLS + col) * 8];
            acc = __builtin_amdgcn_mfma_f32_16x16x32_bf16(a[kb], b, acc, 0, 0, 0);
        }
#pragma unroll
        for (int r = 0; r < 4; ++r) {
            const int row = rowbase + quad * 4 + r;   // C/D: row=(lane>>4)*4+reg, col=lane&15
            if (row < n) Y[(size_t)row * COLS + col] = acc[r];
        }
    }
}

// ---------- gather conv (128-d): hs = relu(...); writes bf16 for next GEMM ----------
__global__ void gather_relu_128(const float* __restrict__ lin,
                                const int* __restrict__ off, const int* __restrict__ degc,
                                const int* __restrict__ ebuf, const float* __restrict__ dis,
                                const float* __restrict__ bias,
                                unsigned short* __restrict__ outb, int n) {
    const int node = blockIdx.x * 4 + (threadIdx.x >> 6);
    const int lane = threadIdx.x & 63;
    if (node >= n) return;
    const float ds = dis[node];
    const float inv = ds * ds;                 // 1/(deg+1)
    const float2* __restrict__ lin2 = (const float2*)lin;
    float2 acc = lin2[(size_t)node * 64 + lane];
    acc.x *= inv; acc.y *= inv;
    const int start = off[node];
    const int cnt = degc[node];
    for (int j = 0; j < cnt; ++j) {
        const int s = ebuf[start + j];
        const float nm = dis[s] * ds;
        const float2 v = lin2[(size_t)s * 64 + lane];
        acc.x = fmaf(v.x, nm, acc.x);
        acc.y = fmaf(v.y, nm, acc.y);
    }
    const float2 bb = ((const float2*)bias)[lane];
    acc.x += bb.x; acc.y += bb.y;
    acc.x = acc.x > 0.0f ? acc.x : 0.0f;
    acc.y = acc.y > 0.0f ? acc.y : 0.0f;
    const unsigned packed = (unsigned)f2bf(acc.x) | ((unsigned)f2bf(acc.y) << 16);
    ((unsigned*)outb)[(size_t)node * 64 + lane] = packed;
}

// ---------- gather conv (64-d): z = sum_nbr lin[s]*norm + lin[d]/deg + b ----------
__global__ void gather_out_64(const float* __restrict__ lin,
                              const int* __restrict__ off, const int* __restrict__ degc,
                              const int* __restrict__ ebuf, const float* __restrict__ dis,
                              const float* __restrict__ bias,
                              float* __restrict__ outp, int n) {
    const int node = blockIdx.x * 4 + (threadIdx.x >> 6);
    const int lane = threadIdx.x & 63;
    if (node >= n) return;
    const float ds = dis[node];
    const float inv = ds * ds;
    float acc = lin[(size_t)node * 64 + lane] * inv;
    const int start = off[node];
    const int cnt = degc[node];
    for (int j = 0; j < cnt; ++j) {
        const int s = ebuf[start + j];
        const float nm = dis[s] * ds;
        acc = fmaf(lin[(size_t)s * 64 + lane], nm, acc);
    }
    outp[(size_t)node * 64 + lane] = acc + bias[lane];
}

// ---------- decoder: p[e] = sigmoid(dot(Z[src], Z[dst])) over 64 dims ----------
__global__ void decoder_kernel(const float* __restrict__ Z,
                               const int* __restrict__ src, const int* __restrict__ dst,
                               float* __restrict__ outp, int e) {
    const int tid = blockIdx.x * blockDim.x + threadIdx.x;
    const int edge = tid >> 4;   // 16 lanes per edge
    const int lane = tid & 15;
    if (edge >= e) return;
    const int s = src[edge], d = dst[edge];
    const float4 a = *(const float4*)&Z[(size_t)s * OUT_D + lane * 4];
    const float4 b = *(const float4*)&Z[(size_t)d * OUT_D + lane * 4];
    float p = a.x * b.x + a.y * b.y + a.z * b.z + a.w * b.w;
    p += __shfl_down(p, 8, 16);
    p += __shfl_down(p, 4, 16);
    p += __shfl_down(p, 2, 16);
    p += __shfl_down(p, 1, 16);
    if (lane == 0) outp[edge] = 1.0f / (1.0f + expf(-p));
}

extern "C" void kernel_launch(void* const* d_in, const int* in_sizes, int n_in,
                              void* d_out, int out_size, void* d_ws, size_t ws_size,
                              hipStream_t stream) {
    const float* xs  = (const float*)d_in[0];
    const float* xt  = (const float*)d_in[1];
    const int* s_ei  = (const int*)d_in[2];
    const int* t_ei  = (const int*)d_in[3];
    const float* W1  = (const float*)d_in[4];
    const float* b1  = (const float*)d_in[5];
    const float* W2  = (const float*)d_in[6];
    const float* b2  = (const float*)d_in[7];
    const float* W3  = (const float*)d_in[8];
    const float* b3  = (const float*)d_in[9];

    // workspace layout (~107 MB)
    float* ws = (float*)d_ws;
    float*          A    = ws;                                        // N*128 f (lin outputs)
    unsigned short* Xb   = (unsigned short*)(A + (size_t)N_NODES * HID); // NPAD*128 bf16
    unsigned short* Hb   = Xb + (size_t)N_PAD * HID;                  // NPAD*128 bf16
    unsigned short* Wp   = Hb + (size_t)N_PAD * HID;                  // 128*128 bf16
    unsigned short* W3p  = Wp + 128 * HID;                            // 128*64 bf16
    float* dis           = (float*)(W3p + 128 * OUT_D);               // N f
    int*   deg_i         = (int*)(dis + N_NODES);                     // N i
    int*   off           = deg_i + N_NODES;                           // N i
    int*   cur           = off + N_NODES;                             // N i
    int*   partial       = cur + N_NODES;                             // 256 i
    int*   ebuf          = partial + 256;                             // E i

    float* out = (float*)d_out;
    float* out_zs = out;                                 // N*64
    float* out_zt = out + (size_t)N_NODES * OUT_D;       // N*64
    float* out_ps = out + 2 * (size_t)N_NODES * OUT_D;   // E
    float* out_pt = out_ps + N_EDGES;                    // E

    const int nodeBlocks = (N_NODES + 3) / 4;            // 4 nodes (waves) per block
    const int n4 = N_NODES * HID / 4;                    // float4 count for convert

    // W3 is shared by both networks: pack once per launch
    pack_w<OUT_D><<<(128 * OUT_D + 255) / 256, 256, 0, stream>>>(W3, W3p);

    auto run_net = [&](const float* x, const int* ei,
                       const float* Wl, const float* bl,
                       float* oz, float* op) {
        const int* src = ei;
        const int* dst = ei + N_EDGES;

        // ---- CSR build (shared by both convs of this network) ----
        hipMemsetAsync(deg_i, 0, (size_t)N_NODES * sizeof(int), stream);
        deg_count_i<<<(N_EDGES + 255) / 256, 256, 0, stream>>>(dst, deg_i, N_EDGES);
        scan_block_sums<<<NBLK_SCAN, SCAN_BLK, 0, stream>>>(deg_i, partial, N_NODES);
        scan_partials<<<1, SCAN_BLK, 0, stream>>>(partial, NBLK_SCAN);
        scan_final<<<NBLK_SCAN, SCAN_BLK, 0, stream>>>(deg_i, partial, off, cur, dis, N_NODES);
        bucket_edges<<<(N_EDGES + 255) / 256, 256, 0, stream>>>(src, dst, cur, ebuf, N_EDGES);

        // ---- conv1/conv2: lin = x @ W (MFMA bf16); gather+relu -> Hb (bf16) ----
        pack_w<HID><<<(128 * HID + 255) / 256, 256, 0, stream>>>(Wl, Wp);
        convert_bf16<<<(n4 + 255) / 256, 256, 0, stream>>>(x, Xb, n4);
        mfma_gemm<HID><<<ROW_BLKS, 256, 0, stream>>>(Xb, Wp, A, N_NODES);
        gather_relu_128<<<nodeBlocks, 256, 0, stream>>>(A, off, deg_i, ebuf, dis, bl, Hb, N_NODES);

        // ---- conv3: lin = hs @ W3 (MFMA bf16); gather -> z (directly to output) ----
        mfma_gemm<OUT_D><<<ROW_BLKS, 256, 0, stream>>>(Hb, W3p, A, N_NODES);
        gather_out_64<<<nodeBlocks, 256, 0, stream>>>(A, off, deg_i, ebuf, dis, b3, oz, N_NODES);

        // ---- decoder ----
        decoder_kernel<<<(int)(((size_t)N_EDGES * 16 + 255) / 256), 256, 0, stream>>>(
            oz, src, dst, op, N_EDGES);
    };

    run_net(xs, s_ei, W1, b1, out_zs, out_ps);
    run_net(xt, t_ei, W2, b2, out_zt, out_pt);
}

// Round 5
// 580.405 us; speedup vs baseline: 5.4952x; 1.1730x over previous
//
#include <hip/hip_runtime.h>
#include <hip/hip_bf16.h>

// Problem constants (match reference)
constexpr int N_NODES = 100000;
constexpr int N_EDGES = 500000;
constexpr int HID     = 128;   // conv1/conv2 output dim
constexpr int OUT_D   = 64;    // conv3 output dim

constexpr int ROW_BLKS = (N_NODES + 63) / 64;   // 1563 blocks of 64 rows
constexpr int N_PAD    = ROW_BLKS * 64;          // 100032 padded rows

constexpr int SCAN_BLK   = 256;
constexpr int SCAN_ELEMS = 1024;                                    // 4 per thread
constexpr int NBLK_SCAN  = (N_NODES + SCAN_ELEMS - 1) / SCAN_ELEMS; // 98 (<=256)

typedef __attribute__((ext_vector_type(8))) short short8;
typedef __attribute__((ext_vector_type(4))) float float4v;

// float -> bf16 (round-to-nearest-even), as raw ushort
__device__ __forceinline__ unsigned short f2bf(float f) {
    unsigned u = __float_as_uint(f);
    u += 0x7fffu + ((u >> 16) & 1u);
    return (unsigned short)(u >> 16);
}
// packed pair of bf16 (lo = even col, hi = odd col) -> two floats
__device__ __forceinline__ float2 bfp2f(unsigned u) {
    float2 r;
    r.x = __uint_as_float(u << 16);
    r.y = __uint_as_float(u & 0xffff0000u);
    return r;
}
__device__ __forceinline__ float bf2f(unsigned short u) {
    return __uint_as_float(((unsigned)u) << 16);
}

// ---------- degree count (int atomics) ----------
__global__ void deg_count_i(const int* __restrict__ dst, int* __restrict__ deg, int e) {
    int i = blockIdx.x * blockDim.x + threadIdx.x;
    if (i < e) atomicAdd(&deg[dst[i]], 1);
}

// ---------- scan phase A: per-block sums of 1024 degrees ----------
__global__ void scan_block_sums(const int* __restrict__ deg, int* __restrict__ partial, int n) {
    __shared__ int sd[SCAN_BLK];
    const int base = blockIdx.x * SCAN_ELEMS;
    int sum = 0;
#pragma unroll
    for (int k = 0; k < 4; ++k) {
        const int idx = base + k * SCAN_BLK + threadIdx.x;
        if (idx < n) sum += deg[idx];
    }
    sd[threadIdx.x] = sum;
    __syncthreads();
    for (int o = SCAN_BLK / 2; o > 0; o >>= 1) {
        if (threadIdx.x < o) sd[threadIdx.x] += sd[threadIdx.x + o];
        __syncthreads();
    }
    if (threadIdx.x == 0) partial[blockIdx.x] = sd[0];
}

// ---------- scan phase B: exclusive-scan the (<=256) partials in place ----------
__global__ void scan_partials(int* __restrict__ partial, int np) {
    __shared__ int s[SCAN_BLK];
    const int t = threadIdx.x;
    const int v = (t < np) ? partial[t] : 0;
    s[t] = v;
    __syncthreads();
    for (int o = 1; o < SCAN_BLK; o <<= 1) {
        const int x = (t >= o) ? s[t - o] : 0;
        __syncthreads();
        if (t >= o) s[t] += x;
        __syncthreads();
    }
    if (t < np) partial[t] = s[t] - v;   // exclusive
}

// ---------- scan phase C: final offsets + cursor copy + dis = rsqrt(deg+1) ----------
__global__ void scan_final(const int* __restrict__ deg, const int* __restrict__ partial,
                           int* __restrict__ off, int* __restrict__ cur,
                           float* __restrict__ dis, int n) {
    __shared__ int s[SCAN_BLK];
    const int t = threadIdx.x;
    const int base = blockIdx.x * SCAN_ELEMS + t * 4;
    int d0 = 0, d1 = 0, d2 = 0, d3 = 0;
    if (base + 0 < n) d0 = deg[base + 0];
    if (base + 1 < n) d1 = deg[base + 1];
    if (base + 2 < n) d2 = deg[base + 2];
    if (base + 3 < n) d3 = deg[base + 3];
    const int ts = d0 + d1 + d2 + d3;
    s[t] = ts;
    __syncthreads();
    for (int o = 1; o < SCAN_BLK; o <<= 1) {
        const int x = (t >= o) ? s[t - o] : 0;
        __syncthreads();
        if (t >= o) s[t] += x;
        __syncthreads();
    }
    int ex = s[t] - ts + partial[blockIdx.x];
    const int o0 = ex, o1 = ex + d0, o2 = o1 + d1, o3 = o2 + d2;
    if (base + 0 < n) { off[base + 0] = o0; cur[base + 0] = o0; dis[base + 0] = rsqrtf((float)d0 + 1.0f); }
    if (base + 1 < n) { off[base + 1] = o1; cur[base + 1] = o1; dis[base + 1] = rsqrtf((float)d1 + 1.0f); }
    if (base + 2 < n) { off[base + 2] = o2; cur[base + 2] = o2; dis[base + 2] = rsqrtf((float)d2 + 1.0f); }
    if (base + 3 < n) { off[base + 3] = o3; cur[base + 3] = o3; dis[base + 3] = rsqrtf((float)d3 + 1.0f); }
}

// ---------- bucket edges by dst (CSR build) ----------
__global__ void bucket_edges(const int* __restrict__ src, const int* __restrict__ dst,
                             int* __restrict__ cur, int* __restrict__ ebuf, int e) {
    const int i = blockIdx.x * blockDim.x + threadIdx.x;
    if (i >= e) return;
    const int d = dst[i];
    const int pos = atomicAdd(&cur[d], 1);
    ebuf[pos] = src[i];
}

// ---------- fp32 -> bf16 conversion (x features) ----------
__global__ void convert_bf16(const float* __restrict__ X, unsigned short* __restrict__ Xb,
                             int n4) {
    const int i = blockIdx.x * blockDim.x + threadIdx.x;
    if (i >= n4) return;
    const float4 v = ((const float4*)X)[i];
    ushort4 o;
    o.x = f2bf(v.x); o.y = f2bf(v.y); o.z = f2bf(v.z); o.w = f2bf(v.w);
    ((ushort4*)Xb)[i] = o;
}

// ---------- pack W[128,COLS] fp32 into MFMA B-fragment order, bf16 ----------
template <int COLS>
__global__ void pack_w(const float* __restrict__ W, unsigned short* __restrict__ Wp) {
    const int idx = blockIdx.x * blockDim.x + threadIdx.x;  // k*COLS + n
    if (idx >= 128 * COLS) return;
    const int k = idx / COLS, nn = idx % COLS;
    const int kb = k >> 5, rem = k & 31, quad = rem >> 3, j = rem & 7;
    Wp[((size_t)(kb * 4 + quad) * COLS + nn) * 8 + j] = f2bf(W[idx]);
}

// ---------- MFMA GEMM: Y[n,COLS](bf16) = Xb[n,128](bf16) @ Wp(bf16, packed) ----
template <int COLS>
__global__ __launch_bounds__(256) void mfma_gemm(const unsigned short* __restrict__ Xb,
                                                 const unsigned short* __restrict__ Wp,
                                                 unsigned short* __restrict__ Y, int n) {
    const int wave = threadIdx.x >> 6;
    const int lane = threadIdx.x & 63;
    const int quad = lane >> 4;
    const int l16  = lane & 15;
    const int rowbase = blockIdx.x * 64 + wave * 16;

    short8 a[4];
    const size_t arow = (size_t)(rowbase + l16) * 128;
#pragma unroll
    for (int kb = 0; kb < 4; ++kb)
        a[kb] = *(const short8*)&Xb[arow + kb * 32 + quad * 8];

#pragma unroll
    for (int ct = 0; ct < COLS / 16; ++ct) {
        const int col = ct * 16 + l16;
        float4v acc = {0.0f, 0.0f, 0.0f, 0.0f};
#pragma unroll
        for (int kb = 0; kb < 4; ++kb) {
            const short8 b = *(const short8*)&Wp[((size_t)(kb * 4 + quad) * COLS + col) * 8];
            acc = __builtin_amdgcn_mfma_f32_16x16x32_bf16(a[kb], b, acc, 0, 0, 0);
        }
#pragma unroll
        for (int r = 0; r < 4; ++r) {
            const int row = rowbase + quad * 4 + r;   // C/D: row=(lane>>4)*4+reg, col=lane&15
            if (row < n) Y[(size_t)row * COLS + col] = f2bf(acc[r]);
        }
    }
}

// ---------- gather conv (128-d, bf16 rows): hs = relu(...) -> bf16 ----------
__global__ void gather_relu_128(const unsigned short* __restrict__ lin,
                                const int* __restrict__ off, const int* __restrict__ degc,
                                const int* __restrict__ ebuf, const float* __restrict__ dis,
                                const float* __restrict__ bias,
                                unsigned short* __restrict__ outb, int n) {
    const int node = blockIdx.x * 4 + (threadIdx.x >> 6);
    const int lane = threadIdx.x & 63;
    if (node >= n) return;
    const float ds = dis[node];
    const float inv = ds * ds;                 // 1/(deg+1)
    const unsigned* __restrict__ linu = (const unsigned*)lin;
    float2 self = bfp2f(linu[(size_t)node * 64 + lane]);
    float2 acc;
    acc.x = self.x * inv; acc.y = self.y * inv;
    const int start = off[node];
    const int cnt = degc[node];
    int j = 0;
    for (; j + 1 < cnt; j += 2) {
        const int s0 = ebuf[start + j];
        const int s1 = ebuf[start + j + 1];
        const float n0 = dis[s0] * ds;
        const float n1 = dis[s1] * ds;
        const unsigned u0 = linu[(size_t)s0 * 64 + lane];
        const unsigned u1 = linu[(size_t)s1 * 64 + lane];
        const float2 v0 = bfp2f(u0);
        const float2 v1 = bfp2f(u1);
        acc.x = fmaf(v0.x, n0, acc.x); acc.y = fmaf(v0.y, n0, acc.y);
        acc.x = fmaf(v1.x, n1, acc.x); acc.y = fmaf(v1.y, n1, acc.y);
    }
    if (j < cnt) {
        const int s = ebuf[start + j];
        const float nm = dis[s] * ds;
        const float2 v = bfp2f(linu[(size_t)s * 64 + lane]);
        acc.x = fmaf(v.x, nm, acc.x); acc.y = fmaf(v.y, nm, acc.y);
    }
    const float2 bb = ((const float2*)bias)[lane];
    acc.x += bb.x; acc.y += bb.y;
    acc.x = acc.x > 0.0f ? acc.x : 0.0f;
    acc.y = acc.y > 0.0f ? acc.y : 0.0f;
    const unsigned packed = (unsigned)f2bf(acc.x) | ((unsigned)f2bf(acc.y) << 16);
    ((unsigned*)outb)[(size_t)node * 64 + lane] = packed;
}

// ---------- gather conv (64-d, bf16 rows): z -> fp32 output ----------
__global__ void gather_out_64(const unsigned short* __restrict__ lin,
                              const int* __restrict__ off, const int* __restrict__ degc,
                              const int* __restrict__ ebuf, const float* __restrict__ dis,
                              const float* __restrict__ bias,
                              float* __restrict__ outp, int n) {
    const int node = blockIdx.x * 4 + (threadIdx.x >> 6);
    const int lane = threadIdx.x & 63;
    if (node >= n) return;
    const float ds = dis[node];
    const float inv = ds * ds;
    float acc = bf2f(lin[(size_t)node * 64 + lane]) * inv;
    const int start = off[node];
    const int cnt = degc[node];
    int j = 0;
    for (; j + 1 < cnt; j += 2) {
        const int s0 = ebuf[start + j];
        const int s1 = ebuf[start + j + 1];
        const float n0 = dis[s0] * ds;
        const float n1 = dis[s1] * ds;
        const float v0 = bf2f(lin[(size_t)s0 * 64 + lane]);
        const float v1 = bf2f(lin[(size_t)s1 * 64 + lane]);
        acc = fmaf(v0, n0, acc);
        acc = fmaf(v1, n1, acc);
    }
    if (j < cnt) {
        const int s = ebuf[start + j];
        acc = fmaf(bf2f(lin[(size_t)s * 64 + lane]), dis[s] * ds, acc);
    }
    outp[(size_t)node * 64 + lane] = acc + bias[lane];
}

// ---------- decoder: p[e] = sigmoid(dot(Z[src], Z[dst])) over 64 dims ----------
__global__ void decoder_kernel(const float* __restrict__ Z,
                               const int* __restrict__ src, const int* __restrict__ dst,
                               float* __restrict__ outp, int e) {
    const int tid = blockIdx.x * blockDim.x + threadIdx.x;
    const int edge = tid >> 4;   // 16 lanes per edge
    const int lane = tid & 15;
    if (edge >= e) return;
    const int s = src[edge], d = dst[edge];
    const float4 a = *(const float4*)&Z[(size_t)s * OUT_D + lane * 4];
    const float4 b = *(const float4*)&Z[(size_t)d * OUT_D + lane * 4];
    float p = a.x * b.x + a.y * b.y + a.z * b.z + a.w * b.w;
    p += __shfl_down(p, 8, 16);
    p += __shfl_down(p, 4, 16);
    p += __shfl_down(p, 2, 16);
    p += __shfl_down(p, 1, 16);
    if (lane == 0) outp[edge] = 1.0f / (1.0f + expf(-p));
}

extern "C" void kernel_launch(void* const* d_in, const int* in_sizes, int n_in,
                              void* d_out, int out_size, void* d_ws, size_t ws_size,
                              hipStream_t stream) {
    const float* xs  = (const float*)d_in[0];
    const float* xt  = (const float*)d_in[1];
    const int* s_ei  = (const int*)d_in[2];
    const int* t_ei  = (const int*)d_in[3];
    const float* W1  = (const float*)d_in[4];
    const float* b1  = (const float*)d_in[5];
    const float* W2  = (const float*)d_in[6];
    const float* b2  = (const float*)d_in[7];
    const float* W3  = (const float*)d_in[8];
    const float* b3  = (const float*)d_in[9];

    // workspace layout (~93 MB, all bf16 feature buffers)
    unsigned short* Xb  = (unsigned short*)d_ws;                 // NPAD*128 bf16 (x)
    unsigned short* Lb  = Xb + (size_t)N_PAD * HID;              // NPAD*128 bf16 (lin conv1)
    unsigned short* Hb  = Lb + (size_t)N_PAD * HID;              // NPAD*128 bf16 (h)
    unsigned short* L2b = Hb + (size_t)N_PAD * HID;              // NPAD*64  bf16 (lin conv3)
    unsigned short* Wp  = L2b + (size_t)N_PAD * OUT_D;           // 128*128 bf16
    unsigned short* W3p = Wp + 128 * HID;                        // 128*64 bf16
    float* dis          = (float*)(W3p + 128 * OUT_D);           // N f
    int*   deg_i        = (int*)(dis + N_NODES);                 // N i
    int*   off          = deg_i + N_NODES;                       // N i
    int*   cur          = off + N_NODES;                         // N i
    int*   partial      = cur + N_NODES;                         // 256 i
    int*   ebuf         = partial + 256;                         // E i

    float* out = (float*)d_out;
    float* out_zs = out;                                 // N*64
    float* out_zt = out + (size_t)N_NODES * OUT_D;       // N*64
    float* out_ps = out + 2 * (size_t)N_NODES * OUT_D;   // E
    float* out_pt = out_ps + N_EDGES;                    // E

    const int nodeBlocks = (N_NODES + 3) / 4;            // 4 nodes (waves) per block
    const int n4 = N_NODES * HID / 4;                    // float4 count for convert

    // W3 is shared by both networks: pack once per launch
    pack_w<OUT_D><<<(128 * OUT_D + 255) / 256, 256, 0, stream>>>(W3, W3p);

    auto run_net = [&](const float* x, const int* ei,
                       const float* Wl, const float* bl,
                       float* oz, float* op) {
        const int* src = ei;
        const int* dst = ei + N_EDGES;

        // ---- CSR build (shared by both convs of this network) ----
        hipMemsetAsync(deg_i, 0, (size_t)N_NODES * sizeof(int), stream);
        deg_count_i<<<(N_EDGES + 255) / 256, 256, 0, stream>>>(dst, deg_i, N_EDGES);
        scan_block_sums<<<NBLK_SCAN, SCAN_BLK, 0, stream>>>(deg_i, partial, N_NODES);
        scan_partials<<<1, SCAN_BLK, 0, stream>>>(partial, NBLK_SCAN);
        scan_final<<<NBLK_SCAN, SCAN_BLK, 0, stream>>>(deg_i, partial, off, cur, dis, N_NODES);
        bucket_edges<<<(N_EDGES + 255) / 256, 256, 0, stream>>>(src, dst, cur, ebuf, N_EDGES);

        // ---- conv1/conv2: lin = x @ W (MFMA bf16 -> bf16); gather+relu -> Hb ----
        pack_w<HID><<<(128 * HID + 255) / 256, 256, 0, stream>>>(Wl, Wp);
        convert_bf16<<<(n4 + 255) / 256, 256, 0, stream>>>(x, Xb, n4);
        mfma_gemm<HID><<<ROW_BLKS, 256, 0, stream>>>(Xb, Wp, Lb, N_NODES);
        gather_relu_128<<<nodeBlocks, 256, 0, stream>>>(Lb, off, deg_i, ebuf, dis, bl, Hb, N_NODES);

        // ---- conv3: lin = hs @ W3 (MFMA bf16 -> bf16); gather -> z (fp32 output) ----
        mfma_gemm<OUT_D><<<ROW_BLKS, 256, 0, stream>>>(Hb, W3p, L2b, N_NODES);
        gather_out_64<<<nodeBlocks, 256, 0, stream>>>(L2b, off, deg_i, ebuf, dis, b3, oz, N_NODES);

        // ---- decoder ----
        decoder_kernel<<<(int)(((size_t)N_EDGES * 16 + 255) / 256), 256, 0, stream>>>(
            oz, src, dst, op, N_EDGES);
    };

    run_net(xs, s_ei, W1, b1, out_zs, out_ps);
    run_net(xt, t_ei, W2, b2, out_zt, out_pt);
}

// Round 6
// 533.356 us; speedup vs baseline: 5.9800x; 1.0882x over previous
//
#include <hip/hip_runtime.h>
#include <hip/hip_bf16.h>

// Problem constants (match reference)
constexpr int N_NODES = 100000;
constexpr int N_EDGES = 500000;
constexpr int HID     = 128;   // conv1/conv2 output dim
constexpr int OUT_D   = 64;    // conv3 output dim

constexpr int ROW_BLKS = (N_NODES + 63) / 64;   // 1563 blocks of 64 rows
constexpr int N_PAD    = ROW_BLKS * 64;          // 100032 padded rows

constexpr int SCAN_BLK   = 256;
constexpr int SCAN_ELEMS = 1024;                                    // 4 per thread
constexpr int NBLK_SCAN  = (N_NODES + SCAN_ELEMS - 1) / SCAN_ELEMS; // 98 (<=256)

typedef __attribute__((ext_vector_type(8))) short short8;
typedef __attribute__((ext_vector_type(4))) float float4v;

// float -> bf16 (round-to-nearest-even), as raw ushort
__device__ __forceinline__ unsigned short f2bf(float f) {
    unsigned u = __float_as_uint(f);
    u += 0x7fffu + ((u >> 16) & 1u);
    return (unsigned short)(u >> 16);
}
// packed pair of bf16 (lo = even col, hi = odd col) -> two floats
__device__ __forceinline__ float2 bfp2f(unsigned u) {
    float2 r;
    r.x = __uint_as_float(u << 16);
    r.y = __uint_as_float(u & 0xffff0000u);
    return r;
}
__device__ __forceinline__ float bf2f(unsigned short u) {
    return __uint_as_float(((unsigned)u) << 16);
}

// ---------- degree count (int atomics) ----------
__global__ void deg_count_i(const int* __restrict__ dst, int* __restrict__ deg, int e) {
    int i = blockIdx.x * blockDim.x + threadIdx.x;
    if (i < e) atomicAdd(&deg[dst[i]], 1);
}

// ---------- scan phase A: per-block sums of 1024 degrees ----------
__global__ void scan_block_sums(const int* __restrict__ deg, int* __restrict__ partial, int n) {
    __shared__ int sd[SCAN_BLK];
    const int base = blockIdx.x * SCAN_ELEMS;
    int sum = 0;
#pragma unroll
    for (int k = 0; k < 4; ++k) {
        const int idx = base + k * SCAN_BLK + threadIdx.x;
        if (idx < n) sum += deg[idx];
    }
    sd[threadIdx.x] = sum;
    __syncthreads();
    for (int o = SCAN_BLK / 2; o > 0; o >>= 1) {
        if (threadIdx.x < o) sd[threadIdx.x] += sd[threadIdx.x + o];
        __syncthreads();
    }
    if (threadIdx.x == 0) partial[blockIdx.x] = sd[0];
}

// ---------- scan phase B: exclusive-scan the (<=256) partials in place ----------
__global__ void scan_partials(int* __restrict__ partial, int np) {
    __shared__ int s[SCAN_BLK];
    const int t = threadIdx.x;
    const int v = (t < np) ? partial[t] : 0;
    s[t] = v;
    __syncthreads();
    for (int o = 1; o < SCAN_BLK; o <<= 1) {
        const int x = (t >= o) ? s[t - o] : 0;
        __syncthreads();
        if (t >= o) s[t] += x;
        __syncthreads();
    }
    if (t < np) partial[t] = s[t] - v;   // exclusive
}

// ---------- scan phase C: final offsets + cursor copy + dis = rsqrt(deg+1) ----------
__global__ void scan_final(const int* __restrict__ deg, const int* __restrict__ partial,
                           int* __restrict__ off, int* __restrict__ cur,
                           float* __restrict__ dis, int n) {
    __shared__ int s[SCAN_BLK];
    const int t = threadIdx.x;
    const int base = blockIdx.x * SCAN_ELEMS + t * 4;
    int d0 = 0, d1 = 0, d2 = 0, d3 = 0;
    if (base + 0 < n) d0 = deg[base + 0];
    if (base + 1 < n) d1 = deg[base + 1];
    if (base + 2 < n) d2 = deg[base + 2];
    if (base + 3 < n) d3 = deg[base + 3];
    const int ts = d0 + d1 + d2 + d3;
    s[t] = ts;
    __syncthreads();
    for (int o = 1; o < SCAN_BLK; o <<= 1) {
        const int x = (t >= o) ? s[t - o] : 0;
        __syncthreads();
        if (t >= o) s[t] += x;
        __syncthreads();
    }
    int ex = s[t] - ts + partial[blockIdx.x];
    const int o0 = ex, o1 = ex + d0, o2 = o1 + d1, o3 = o2 + d2;
    if (base + 0 < n) { off[base + 0] = o0; cur[base + 0] = o0; dis[base + 0] = rsqrtf((float)d0 + 1.0f); }
    if (base + 1 < n) { off[base + 1] = o1; cur[base + 1] = o1; dis[base + 1] = rsqrtf((float)d1 + 1.0f); }
    if (base + 2 < n) { off[base + 2] = o2; cur[base + 2] = o2; dis[base + 2] = rsqrtf((float)d2 + 1.0f); }
    if (base + 3 < n) { off[base + 3] = o3; cur[base + 3] = o3; dis[base + 3] = rsqrtf((float)d3 + 1.0f); }
}

// ---------- bucket edges by dst (CSR build) ----------
__global__ void bucket_edges(const int* __restrict__ src, const int* __restrict__ dst,
                             int* __restrict__ cur, int* __restrict__ ebuf, int e) {
    const int i = blockIdx.x * blockDim.x + threadIdx.x;
    if (i >= e) return;
    const int d = dst[i];
    const int pos = atomicAdd(&cur[d], 1);
    ebuf[pos] = src[i];
}

// ---------- fp32 -> bf16 conversion (x features) ----------
__global__ void convert_bf16(const float* __restrict__ X, unsigned short* __restrict__ Xb,
                             int n4) {
    const int i = blockIdx.x * blockDim.x + threadIdx.x;
    if (i >= n4) return;
    const float4 v = ((const float4*)X)[i];
    ushort4 o;
    o.x = f2bf(v.x); o.y = f2bf(v.y); o.z = f2bf(v.z); o.w = f2bf(v.w);
    ((ushort4*)Xb)[i] = o;
}

// ---------- pack W[128,COLS] fp32 into MFMA B-fragment order, bf16 ----------
template <int COLS>
__global__ void pack_w(const float* __restrict__ W, unsigned short* __restrict__ Wp) {
    const int idx = blockIdx.x * blockDim.x + threadIdx.x;  // k*COLS + n
    if (idx >= 128 * COLS) return;
    const int k = idx / COLS, nn = idx % COLS;
    const int kb = k >> 5, rem = k & 31, quad = rem >> 3, j = rem & 7;
    Wp[((size_t)(kb * 4 + quad) * COLS + nn) * 8 + j] = f2bf(W[idx]);
}

// ---------- MFMA GEMM: Y[n,COLS](bf16) = Xb[n,128](bf16) @ Wp(bf16, packed) ----
template <int COLS>
__global__ __launch_bounds__(256) void mfma_gemm(const unsigned short* __restrict__ Xb,
                                                 const unsigned short* __restrict__ Wp,
                                                 unsigned short* __restrict__ Y, int n) {
    const int wave = threadIdx.x >> 6;
    const int lane = threadIdx.x & 63;
    const int quad = lane >> 4;
    const int l16  = lane & 15;
    const int rowbase = blockIdx.x * 64 + wave * 16;

    short8 a[4];
    const size_t arow = (size_t)(rowbase + l16) * 128;
#pragma unroll
    for (int kb = 0; kb < 4; ++kb)
        a[kb] = *(const short8*)&Xb[arow + kb * 32 + quad * 8];

#pragma unroll
    for (int ct = 0; ct < COLS / 16; ++ct) {
        const int col = ct * 16 + l16;
        float4v acc = {0.0f, 0.0f, 0.0f, 0.0f};
#pragma unroll
        for (int kb = 0; kb < 4; ++kb) {
            const short8 b = *(const short8*)&Wp[((size_t)(kb * 4 + quad) * COLS + col) * 8];
            acc = __builtin_amdgcn_mfma_f32_16x16x32_bf16(a[kb], b, acc, 0, 0, 0);
        }
#pragma unroll
        for (int r = 0; r < 4; ++r) {
            const int row = rowbase + quad * 4 + r;   // C/D: row=(lane>>4)*4+reg, col=lane&15
            if (row < n) Y[(size_t)row * COLS + col] = f2bf(acc[r]);
        }
    }
}

// ---------- gather conv (128-d, bf16 rows): hs = relu(...) -> bf16 ----------
__global__ void gather_relu_128(const unsigned short* __restrict__ lin,
                                const int* __restrict__ off, const int* __restrict__ degc,
                                const int* __restrict__ ebuf, const float* __restrict__ dis,
                                const float* __restrict__ bias,
                                unsigned short* __restrict__ outb, int n) {
    const int node = blockIdx.x * 4 + (threadIdx.x >> 6);
    const int lane = threadIdx.x & 63;
    if (node >= n) return;
    const float ds = dis[node];
    const float inv = ds * ds;                 // 1/(deg+1)
    const unsigned* __restrict__ linu = (const unsigned*)lin;
    float2 self = bfp2f(linu[(size_t)node * 64 + lane]);
    float2 acc;
    acc.x = self.x * inv; acc.y = self.y * inv;
    const int start = off[node];
    const int cnt = degc[node];
    int j = 0;
    for (; j + 3 < cnt; j += 4) {
        const int s0 = ebuf[start + j + 0];
        const int s1 = ebuf[start + j + 1];
        const int s2 = ebuf[start + j + 2];
        const int s3 = ebuf[start + j + 3];
        const float n0 = dis[s0] * ds;
        const float n1 = dis[s1] * ds;
        const float n2 = dis[s2] * ds;
        const float n3 = dis[s3] * ds;
        const unsigned u0 = linu[(size_t)s0 * 64 + lane];
        const unsigned u1 = linu[(size_t)s1 * 64 + lane];
        const unsigned u2 = linu[(size_t)s2 * 64 + lane];
        const unsigned u3 = linu[(size_t)s3 * 64 + lane];
        const float2 v0 = bfp2f(u0), v1 = bfp2f(u1), v2 = bfp2f(u2), v3 = bfp2f(u3);
        acc.x = fmaf(v0.x, n0, acc.x); acc.y = fmaf(v0.y, n0, acc.y);
        acc.x = fmaf(v1.x, n1, acc.x); acc.y = fmaf(v1.y, n1, acc.y);
        acc.x = fmaf(v2.x, n2, acc.x); acc.y = fmaf(v2.y, n2, acc.y);
        acc.x = fmaf(v3.x, n3, acc.x); acc.y = fmaf(v3.y, n3, acc.y);
    }
    for (; j < cnt; ++j) {
        const int s = ebuf[start + j];
        const float nm = dis[s] * ds;
        const float2 v = bfp2f(linu[(size_t)s * 64 + lane]);
        acc.x = fmaf(v.x, nm, acc.x); acc.y = fmaf(v.y, nm, acc.y);
    }
    const float2 bb = ((const float2*)bias)[lane];
    acc.x += bb.x; acc.y += bb.y;
    acc.x = acc.x > 0.0f ? acc.x : 0.0f;
    acc.y = acc.y > 0.0f ? acc.y : 0.0f;
    const unsigned packed = (unsigned)f2bf(acc.x) | ((unsigned)f2bf(acc.y) << 16);
    ((unsigned*)outb)[(size_t)node * 64 + lane] = packed;
}

// ---------- gather conv (64-d, bf16 rows): z -> fp32 output + bf16 copy ----------
__global__ void gather_out_64(const unsigned short* __restrict__ lin,
                              const int* __restrict__ off, const int* __restrict__ degc,
                              const int* __restrict__ ebuf, const float* __restrict__ dis,
                              const float* __restrict__ bias,
                              float* __restrict__ outp, unsigned short* __restrict__ zb,
                              int n) {
    const int node = blockIdx.x * 4 + (threadIdx.x >> 6);
    const int lane = threadIdx.x & 63;
    if (node >= n) return;
    const float ds = dis[node];
    const float inv = ds * ds;
    float acc = bf2f(lin[(size_t)node * 64 + lane]) * inv;
    const int start = off[node];
    const int cnt = degc[node];
    int j = 0;
    for (; j + 3 < cnt; j += 4) {
        const int s0 = ebuf[start + j + 0];
        const int s1 = ebuf[start + j + 1];
        const int s2 = ebuf[start + j + 2];
        const int s3 = ebuf[start + j + 3];
        const float n0 = dis[s0] * ds;
        const float n1 = dis[s1] * ds;
        const float n2 = dis[s2] * ds;
        const float n3 = dis[s3] * ds;
        const float v0 = bf2f(lin[(size_t)s0 * 64 + lane]);
        const float v1 = bf2f(lin[(size_t)s1 * 64 + lane]);
        const float v2 = bf2f(lin[(size_t)s2 * 64 + lane]);
        const float v3 = bf2f(lin[(size_t)s3 * 64 + lane]);
        acc = fmaf(v0, n0, acc);
        acc = fmaf(v1, n1, acc);
        acc = fmaf(v2, n2, acc);
        acc = fmaf(v3, n3, acc);
    }
    for (; j < cnt; ++j) {
        const int s = ebuf[start + j];
        acc = fmaf(bf2f(lin[(size_t)s * 64 + lane]), dis[s] * ds, acc);
    }
    const float z = acc + bias[lane];
    outp[(size_t)node * 64 + lane] = z;
    zb[(size_t)node * 64 + lane] = f2bf(z);
}

// ---------- decoder (bf16 z): p[e] = sigmoid(dot(Z[src], Z[dst])) ----------
__global__ void decoder_kernel(const unsigned short* __restrict__ Zb,
                               const int* __restrict__ src, const int* __restrict__ dst,
                               float* __restrict__ outp, int e) {
    const int tid = blockIdx.x * blockDim.x + threadIdx.x;
    const int edge = tid >> 3;   // 8 lanes per edge
    const int lane = tid & 7;
    if (edge >= e) return;
    const int s = src[edge], d = dst[edge];
    const uint4 ua = *(const uint4*)&Zb[(size_t)s * OUT_D + lane * 8];
    const uint4 ub = *(const uint4*)&Zb[(size_t)d * OUT_D + lane * 8];
    float p = 0.0f;
    {
        const float2 a0 = bfp2f(ua.x), b0 = bfp2f(ub.x);
        const float2 a1 = bfp2f(ua.y), b1 = bfp2f(ub.y);
        const float2 a2 = bfp2f(ua.z), b2 = bfp2f(ub.z);
        const float2 a3 = bfp2f(ua.w), b3 = bfp2f(ub.w);
        p = fmaf(a0.x, b0.x, p); p = fmaf(a0.y, b0.y, p);
        p = fmaf(a1.x, b1.x, p); p = fmaf(a1.y, b1.y, p);
        p = fmaf(a2.x, b2.x, p); p = fmaf(a2.y, b2.y, p);
        p = fmaf(a3.x, b3.x, p); p = fmaf(a3.y, b3.y, p);
    }
    p += __shfl_down(p, 4, 8);
    p += __shfl_down(p, 2, 8);
    p += __shfl_down(p, 1, 8);
    if (lane == 0) outp[edge] = 1.0f / (1.0f + expf(-p));
}

extern "C" void kernel_launch(void* const* d_in, const int* in_sizes, int n_in,
                              void* d_out, int out_size, void* d_ws, size_t ws_size,
                              hipStream_t stream) {
    const float* xs  = (const float*)d_in[0];
    const float* xt  = (const float*)d_in[1];
    const int* s_ei  = (const int*)d_in[2];
    const int* t_ei  = (const int*)d_in[3];
    const float* W1  = (const float*)d_in[4];
    const float* b1  = (const float*)d_in[5];
    const float* W2  = (const float*)d_in[6];
    const float* b2  = (const float*)d_in[7];
    const float* W3  = (const float*)d_in[8];
    const float* b3  = (const float*)d_in[9];

    // workspace layout (~93 MB, all bf16 feature buffers)
    unsigned short* Xb  = (unsigned short*)d_ws;                 // NPAD*128 bf16 (x)
    unsigned short* Lb  = Xb + (size_t)N_PAD * HID;              // NPAD*128 bf16 (lin conv1)
    unsigned short* Hb  = Lb + (size_t)N_PAD * HID;              // NPAD*128 bf16 (h)
    unsigned short* L2b = Hb + (size_t)N_PAD * HID;              // NPAD*64  bf16 (lin conv3)
    unsigned short* Zb  = L2b + (size_t)N_PAD * OUT_D;           // NPAD*64  bf16 (z copy)
    unsigned short* Wp  = Zb + (size_t)N_PAD * OUT_D;            // 128*128 bf16
    unsigned short* W3p = Wp + 128 * HID;                        // 128*64 bf16
    float* dis          = (float*)(W3p + 128 * OUT_D);           // N f
    int*   deg_i        = (int*)(dis + N_NODES);                 // N i
    int*   off          = deg_i + N_NODES;                       // N i
    int*   cur          = off + N_NODES;                         // N i
    int*   partial      = cur + N_NODES;                         // 256 i
    int*   ebuf         = partial + 256;                         // E i

    float* out = (float*)d_out;
    float* out_zs = out;                                 // N*64
    float* out_zt = out + (size_t)N_NODES * OUT_D;       // N*64
    float* out_ps = out + 2 * (size_t)N_NODES * OUT_D;   // E
    float* out_pt = out_ps + N_EDGES;                    // E

    const int nodeBlocks = (N_NODES + 3) / 4;            // 4 nodes (waves) per block
    const int n4 = N_NODES * HID / 4;                    // float4 count for convert

    // W3 is shared by both networks: pack once per launch
    pack_w<OUT_D><<<(128 * OUT_D + 255) / 256, 256, 0, stream>>>(W3, W3p);

    auto run_net = [&](const float* x, const int* ei,
                       const float* Wl, const float* bl,
                       float* oz, float* op) {
        const int* src = ei;
        const int* dst = ei + N_EDGES;

        // ---- CSR build (shared by both convs of this network) ----
        hipMemsetAsync(deg_i, 0, (size_t)N_NODES * sizeof(int), stream);
        deg_count_i<<<(N_EDGES + 255) / 256, 256, 0, stream>>>(dst, deg_i, N_EDGES);
        scan_block_sums<<<NBLK_SCAN, SCAN_BLK, 0, stream>>>(deg_i, partial, N_NODES);
        scan_partials<<<1, SCAN_BLK, 0, stream>>>(partial, NBLK_SCAN);
        scan_final<<<NBLK_SCAN, SCAN_BLK, 0, stream>>>(deg_i, partial, off, cur, dis, N_NODES);
        bucket_edges<<<(N_EDGES + 255) / 256, 256, 0, stream>>>(src, dst, cur, ebuf, N_EDGES);

        // ---- conv1/conv2: lin = x @ W (MFMA bf16 -> bf16); gather+relu -> Hb ----
        pack_w<HID><<<(128 * HID + 255) / 256, 256, 0, stream>>>(Wl, Wp);
        convert_bf16<<<(n4 + 255) / 256, 256, 0, stream>>>(x, Xb, n4);
        mfma_gemm<HID><<<ROW_BLKS, 256, 0, stream>>>(Xb, Wp, Lb, N_NODES);
        gather_relu_128<<<nodeBlocks, 256, 0, stream>>>(Lb, off, deg_i, ebuf, dis, bl, Hb, N_NODES);

        // ---- conv3: lin = hs @ W3 (MFMA bf16 -> bf16); gather -> z + bf16 copy ----
        mfma_gemm<OUT_D><<<ROW_BLKS, 256, 0, stream>>>(Hb, W3p, L2b, N_NODES);
        gather_out_64<<<nodeBlocks, 256, 0, stream>>>(L2b, off, deg_i, ebuf, dis, b3,
                                                      oz, Zb, N_NODES);

        // ---- decoder (bf16 z reads) ----
        decoder_kernel<<<(int)(((size_t)N_EDGES * 8 + 255) / 256), 256, 0, stream>>>(
            Zb, src, dst, op, N_EDGES);
    };

    run_net(xs, s_ei, W1, b1, out_zs, out_ps);
    run_net(xt, t_ei, W2, b2, out_zt, out_pt);
}